// Round 2
// baseline (81.504 us; speedup 1.0000x reference)
//
#include <hip/hip_runtime.h>

#define NN 8
#define CC 16
#define HH 32
#define WW 32
#define OCH 64
#define OH 30
#define OW 30
#define KTOT 144   // 3*3*16

// ws layout (floats): [0..9215]   E[i][oc] = exp(k_flat[i][oc] + 5)
//                     [9216..9279] coef[oc] = bias[oc] - dx * sum_i k_flat[i][oc]
__global__ __launch_bounds__(256) void prep_kernel(
    const float* __restrict__ kw_, const float* __restrict__ bias,
    const float* __restrict__ pdx, float* __restrict__ ws)
{
    const int b = blockIdx.x, t = threadIdx.x;
    if (b < 36) {
        const int idx = b * 256 + t;
        ws[idx] = __expf(kw_[idx] + 5.0f);
    } else if (t < OCH) {
        float s = 0.f;
#pragma unroll 8
        for (int i = 0; i < KTOT; ++i) s += kw_[i * OCH + t];
        ws[9216 + t] = bias[t] - pdx[0] * s;
    }
}

// Each block: one (n, y) output row. 128 threads = 8 xo-quads x 16 oc-groups.
// Thread computes a 4(xo) x 4(oc) register tile.
__global__ __launch_bounds__(128) void bm_main_kernel(
    const float* __restrict__ x, const float* __restrict__ ws,
    const float* __restrict__ pdw, float* __restrict__ out)
{
    __shared__ __align__(16) float sE[KTOT * OCH];   // 36 KB, [i][oc]
    __shared__ __align__(16) float sA[3 * CC * 36];  // [kh][c][w], w-stride 36 (pad w=32..35 zero)
    __shared__ float sRawDW[32];
    __shared__ float sCoef[OCH];

    const int t = threadIdx.x;
    const int n = blockIdx.x / OH;
    const int y = blockIdx.x % OH;

    // ---- stage E (9216 floats = 2304 float4, 18 per thread) ----
    {
        const float4* __restrict__ src = (const float4*)ws;
        float4* dst = (float4*)sE;
        for (int i = t; i < KTOT * OCH / 4; i += 128) dst[i] = src[i];
    }
    // ---- stage clamped A: [kh][c][w] ----
    for (int idx = t; idx < 3 * CC * WW; idx += 128) {
        const int w = idx & 31;
        const int rest = idx >> 5;                // kh*16 + c
        const float v = x[(((n * CC) + (rest & 15)) * HH + (y + (rest >> 4))) * WW + w];
        sA[rest * 36 + w] = fmaxf(v + 5.0f, 1e-12f);
    }
    // zero the pad columns w = 32..35
    for (int idx = t; idx < 3 * CC * 4; idx += 128)
        sA[(idx >> 2) * 36 + 32 + (idx & 3)] = 0.f;
    // ---- coef -> LDS ----
    if (t < OCH) sCoef[t] = ws[9216 + t];
    // ---- raw box sums (unclamped; exact reference semantics) ----
    if (t < 32) {
        float s = 0.f;
        if (t < OW) {
            for (int kh = 0; kh < 3; ++kh)
#pragma unroll
                for (int c = 0; c < CC; ++c) {
                    const float* p = &x[((n * CC + c) * HH + (y + kh)) * WW + t];
                    s += p[0] + p[1] + p[2];
                }
        }
        sRawDW[t] = s * pdw[0];
    }
    __syncthreads();

    const int q  = t & 7;    // xo = 4q + xi
    const int og = t >> 3;   // oc = 4*og + j

    float acc[4][4];
#pragma unroll
    for (int xi = 0; xi < 4; ++xi)
#pragma unroll
        for (int j = 0; j < 4; ++j) acc[xi][j] = 0.f;

#pragma unroll
    for (int kh = 0; kh < 3; ++kh) {
#pragma unroll 4
        for (int c = 0; c < CC; ++c) {
            const float* arow = &sA[(kh * CC + c) * 36 + 4 * q];
            const float4 a0 = *(const float4*)arow;        // w: 4q .. 4q+3
            const float2 a1 = *(const float2*)(arow + 4);  // w: 4q+4, 4q+5
            const float a[6] = {a0.x, a0.y, a0.z, a0.w, a1.x, a1.y};
#pragma unroll
            for (int kwi = 0; kwi < 3; ++kwi) {
                const float4 e = *(const float4*)&sE[((kh * 3 + kwi) * CC + c) * OCH + 4 * og];
#pragma unroll
                for (int xi = 0; xi < 4; ++xi) {
                    const float av = a[xi + kwi];
                    acc[xi][0] = fmaf(av, e.x, acc[xi][0]);
                    acc[xi][1] = fmaf(av, e.y, acc[xi][1]);
                    acc[xi][2] = fmaf(av, e.z, acc[xi][2]);
                    acc[xi][3] = fmaf(av, e.w, acc[xi][3]);
                }
            }
        }
    }

    // ---- epilogue ----
#pragma unroll
    for (int xi = 0; xi < 4; ++xi) {
        const int xo = 4 * q + xi;
        if (xo < OW) {
#pragma unroll
            for (int j = 0; j < 4; ++j) {
                const int oc = 4 * og + j;
                out[((n * OCH + oc) * OH + y) * OW + xo] = acc[xi][j] - sRawDW[xo] + sCoef[oc];
            }
        }
    }
}

extern "C" void kernel_launch(void* const* d_in, const int* in_sizes, int n_in,
                              void* d_out, int out_size, void* d_ws, size_t ws_size,
                              hipStream_t stream) {
    const float* x    = (const float*)d_in[0];
    const float* k    = (const float*)d_in[1];
    const float* bias = (const float*)d_in[2];
    const float* pdx  = (const float*)d_in[3];
    const float* pdw  = (const float*)d_in[4];
    float* out = (float*)d_out;
    float* ws  = (float*)d_ws;

    prep_kernel<<<37, 256, 0, stream>>>(k, bias, pdx, ws);
    bm_main_kernel<<<NN * OH, 128, 0, stream>>>(x, ws, pdw, out);
}

// Round 3
// 78.213 us; speedup vs baseline: 1.0421x; 1.0421x over previous
//
#include <hip/hip_runtime.h>

#define NN 8
#define CC 16
#define HH 32
#define WW 32
#define OCH 64
#define OH 30
#define OW 30
#define KTOT 144   // 3*3*16

// Single fused kernel. Each block: one (n, y) output row.
// 128 threads = 8 xo-quads x 16 oc-groups; thread owns a 4(xo) x 4(oc) tile.
// y[n,oc,p] = sum_i max(patch_i+5,1e-12)*exp(k[i,oc]+5) - dw*sum_i raw_i
//             - dx*sum_i k[i,oc] + bias[oc]
__global__ __launch_bounds__(128) void bm_fused_kernel(
    const float* __restrict__ x, const float* __restrict__ kw_,
    const float* __restrict__ bias, const float* __restrict__ pdx,
    const float* __restrict__ pdw, float* __restrict__ out)
{
    __shared__ __align__(16) float sE[KTOT * OCH];   // 36 KB, exp(k+5) [i][oc]
    __shared__ __align__(16) float sA[3 * CC * 36];  // [kh][c][w], w-stride 36, pad zeroed
    __shared__ float sRawDW[32];
    __shared__ float sCoef[OCH];

    const int t = threadIdx.x;
    const int n = blockIdx.x / OH;
    const int y = blockIdx.x % OH;

    // ---- stage E = exp(k+5): float4 global loads (L2-resident), 18/thread ----
    {
        const float4* __restrict__ src = (const float4*)kw_;
        float4* dst = (float4*)sE;
        for (int i = t; i < KTOT * OCH / 4; i += 128) {
            float4 v = src[i];
            v.x = __expf(v.x + 5.0f);
            v.y = __expf(v.y + 5.0f);
            v.z = __expf(v.z + 5.0f);
            v.w = __expf(v.w + 5.0f);
            dst[i] = v;
        }
    }
    // ---- stage clamped A: [kh][c][w] ----
    for (int idx = t; idx < 3 * CC * WW; idx += 128) {
        const int w = idx & 31;
        const int rest = idx >> 5;                // kh*16 + c
        const float v = x[(((n * CC) + (rest & 15)) * HH + (y + (rest >> 4))) * WW + w];
        sA[rest * 36 + w] = fmaxf(v + 5.0f, 1e-12f);
    }
    for (int idx = t; idx < 3 * CC * 4; idx += 128)        // zero pad cols 32..35
        sA[(idx >> 2) * 36 + 32 + (idx & 3)] = 0.f;
    // ---- coef[oc] = bias - dx * sum_i k[i,oc] (L2-hit strided reads) ----
    if (t < OCH) {
        float s = 0.f;
#pragma unroll 8
        for (int i = 0; i < KTOT; ++i) s += kw_[i * OCH + t];
        sCoef[t] = bias[t] - pdx[0] * s;
    }
    // ---- raw box sums (unclamped, exact reference semantics) ----
    if (t >= 64 && t < 96) {
        const int xo = t - 64;
        float s = 0.f;
        if (xo < OW) {
            for (int kh = 0; kh < 3; ++kh)
#pragma unroll
                for (int c = 0; c < CC; ++c) {
                    const float* p = &x[((n * CC + c) * HH + (y + kh)) * WW + xo];
                    s += p[0] + p[1] + p[2];
                }
        }
        if (xo < 32) sRawDW[xo] = s * pdw[0];
    }
    __syncthreads();

    const int q  = t & 7;    // xo = 4q + xi
    const int og = t >> 3;   // oc = 4*og + j

    float acc[4][4];
#pragma unroll
    for (int xi = 0; xi < 4; ++xi)
#pragma unroll
        for (int j = 0; j < 4; ++j) acc[xi][j] = 0.f;

#pragma unroll
    for (int kh = 0; kh < 3; ++kh) {
#pragma unroll 4
        for (int c = 0; c < CC; ++c) {
            const float* arow = &sA[(kh * CC + c) * 36 + 4 * q];
            const float4 a0 = *(const float4*)arow;        // w: 4q .. 4q+3
            const float2 a1 = *(const float2*)(arow + 4);  // w: 4q+4, 4q+5
            const float a[6] = {a0.x, a0.y, a0.z, a0.w, a1.x, a1.y};
#pragma unroll
            for (int kwi = 0; kwi < 3; ++kwi) {
                const float4 e = *(const float4*)&sE[((kh * 3 + kwi) * CC + c) * OCH + 4 * og];
#pragma unroll
                for (int xi = 0; xi < 4; ++xi) {
                    const float av = a[xi + kwi];
                    acc[xi][0] = fmaf(av, e.x, acc[xi][0]);
                    acc[xi][1] = fmaf(av, e.y, acc[xi][1]);
                    acc[xi][2] = fmaf(av, e.z, acc[xi][2]);
                    acc[xi][3] = fmaf(av, e.w, acc[xi][3]);
                }
            }
        }
    }

    // ---- epilogue ----
#pragma unroll
    for (int xi = 0; xi < 4; ++xi) {
        const int xo = 4 * q + xi;
        if (xo < OW) {
#pragma unroll
            for (int j = 0; j < 4; ++j) {
                const int oc = 4 * og + j;
                out[((n * OCH + oc) * OH + y) * OW + xo] = acc[xi][j] - sRawDW[xo] + sCoef[oc];
            }
        }
    }
}

extern "C" void kernel_launch(void* const* d_in, const int* in_sizes, int n_in,
                              void* d_out, int out_size, void* d_ws, size_t ws_size,
                              hipStream_t stream) {
    const float* x    = (const float*)d_in[0];
    const float* k    = (const float*)d_in[1];
    const float* bias = (const float*)d_in[2];
    const float* pdx  = (const float*)d_in[3];
    const float* pdw  = (const float*)d_in[4];
    float* out = (float*)d_out;

    bm_fused_kernel<<<NN * OH, 128, 0, stream>>>(x, k, bias, pdx, pdw, out);
}